// Round 4
// baseline (101.209 us; speedup 1.0000x reference)
//
#include <hip/hip_runtime.h>
#include <hip/hip_bf16.h>

#define BROWS 131072
#define CCOLS 64
#define RPB   128           // rows per block
#define LSTR  129           // LDS column stride (odd => 2 lanes/bank on reads AND writes = free)

// 0.5 * weight for distance i (the 0.5 from relu(d) = 0.5*(d+|d|))
__host__ __device__ constexpr float WP(int i) {
    return 0.5f / ((float)BROWS * (float)(CCOLS - i));
}
// coefficient of prefix-sum p_m in the folded linear term: WP(m) + WP(64-m)
__host__ __device__ constexpr float CM(int m) {
    return WP(m) + WP(CCOLS - m);
}
// sum of WP(i) over the parity class this thread owns
__host__ __device__ constexpr float WSUM(int parity) {
    float s = 0.f;
    for (int i = 1; i < CCOLS; ++i)
        if ((i & 1) == parity) s += WP(i);
    return s;
}

// Same math as R2 (passed, absmax 0). New: coalesced global->LDS staging.
// Old path: thread-per-row float4 loads = 256B-stride gather (uncoalesced).
// New path: block loads 128 rows x 256 B contiguously (16 B/lane), stores
// transposed in LDS (stride 129 -> conflict-free), threads read rows via
// ds_read_b32 with immediate offsets.
__global__ __launch_bounds__(256) void mrl_kernel(
    const float* __restrict__ cand,   // [B, C] row-major
    const float* __restrict__ summ,   // [B]
    float* __restrict__ out)          // [1], pre-zeroed
{
    __shared__ float lds[(CCOLS - 1) * LSTR + RPB];  // addr = c*129 + r

    const int tid  = threadIdx.x;
    const int half = tid >> 7;            // 0: even i + summary, 1: odd i
    const int rloc = tid & 127;           // local row
    const int r0   = blockIdx.x * RPB;

    // ---- coalesced staging: 2048 float4 per block, 8 per thread ----
    const float4* g4 = reinterpret_cast<const float4*>(cand + (size_t)r0 * CCOLS);
#pragma unroll
    for (int k = 0; k < 8; ++k) {
        const int idx = tid + k * 256;        // float4 index in block chunk
        const float4 v = g4[idx];
        const int row = idx >> 4;             // 16 float4 per row
        const int c4  = idx & 15;
        lds[(c4 * 4 + 0) * LSTR + row] = v.x;
        lds[(c4 * 4 + 1) * LSTR + row] = v.y;
        lds[(c4 * 4 + 2) * LSTR + row] = v.z;
        lds[(c4 * 4 + 3) * LSTR + row] = v.w;
    }
    const float s = summ[r0 + rloc];
    __syncthreads();

    // ---- row -> registers: 64x ds_read_b32, bank-free (2 lanes/bank) ----
    float x[CCOLS];
#pragma unroll
    for (int c = 0; c < CCOLS; ++c)
        x[c] = lds[c * LSTR + rloc];

    // ---- summary |x - s| part (pre-transform), half 0 only ----
    float sa = 0.f;
    if (half == 0) {
        float sa0 = 0.f, sa1 = 0.f;
#pragma unroll
        for (int c = 0; c < CCOLS; c += 2) {
            sa0 += fabsf(x[c]     - s);
            sa1 += fabsf(x[c + 1] - s);
        }
        sa = sa0 + sa1;
    }

    // ---- transform: y[c] = x[c] + 0.01*c (margin folded into values) ----
#pragma unroll
    for (int c = 0; c < CCOLS; ++c)
        x[c] = fmaf(0.01f, (float)c, x[c]);

    // ---- T = sum of y (4-way tree) ----
    float t0 = 0.f, t1 = 0.f, t2 = 0.f, t3 = 0.f;
#pragma unroll
    for (int c = 0; c < CCOLS; c += 4) {
        t0 += x[c]; t1 += x[c + 1]; t2 += x[c + 2]; t3 += x[c + 3];
    }
    const float T = (t0 + t1) + (t2 + t3);

    float total = 0.f;

    // ---- streaming prefix sums fold the telescoping linear term ----
    if (half == 0) {
        float p = 0.f;
#pragma unroll
        for (int m = 2; m <= 62; m += 2) {
            p += x[m - 2] + x[m - 1];
            total = fmaf(-CM(m), p, total);
        }
        total = fmaf(WSUM(0), T, total);
        // summary: mean relu(x-s) = 0.5/(B*C) * ((T0 - 64*s) + sum|x-s|),
        // T0 = sum of original x = T - 0.01*(0+1+...+63) = T - 20.16
        const float T0 = T - 20.16f;
        total = fmaf(0.5f / ((float)BROWS * (float)CCOLS),
                     (T0 - 64.f * s) + sa, total);
    } else {
        float p = x[0];
        total = fmaf(-CM(1), p, total);
#pragma unroll
        for (int m = 3; m <= 63; m += 2) {
            p += x[m - 2] + x[m - 1];
            total = fmaf(-CM(m), p, total);
        }
        total = fmaf(WSUM(1), T, total);
    }

    // ---- |difference| sums: 2 VALU/pair (v_sub + v_add with abs modifier) ----
#pragma unroll
    for (int i = 1; i < CCOLS; ++i) {
        if ((i & 1) == (half ? 1 : 0)) {
            float a0 = 0.f, a1 = 0.f;
            const int n = CCOLS - i;
#pragma unroll
            for (int j = 0; j < n; ++j) {
                const float d = fabsf(x[j + i] - x[j]);
                if (j & 1) a1 += d; else a0 += d;
            }
            total = fmaf(WP(i), a0 + a1, total);
        }
    }

    // ---- wave64 + block reduction, one atomic per block ----
#pragma unroll
    for (int off = 32; off > 0; off >>= 1)
        total += __shfl_down(total, off, 64);

    __shared__ float ws[4];
    const int lane = tid & 63;
    const int w = tid >> 6;
    if (lane == 0) ws[w] = total;
    __syncthreads();
    if (tid == 0) {
        float t = ws[0] + ws[1] + ws[2] + ws[3];
        atomicAdd(out, t);
    }
}

extern "C" void kernel_launch(void* const* d_in, const int* in_sizes, int n_in,
                              void* d_out, int out_size, void* d_ws, size_t ws_size,
                              hipStream_t stream) {
    const float* cand = (const float*)d_in[0];
    const float* summ = (const float*)d_in[1];
    float* out = (float*)d_out;

    // d_out is re-poisoned to 0xAA before every timed replay — zero it here.
    hipMemsetAsync(out, 0, sizeof(float), stream);

    const int threads = 256;
    const int blocks = BROWS / RPB;  // 1024
    mrl_kernel<<<blocks, threads, 0, stream>>>(cand, summ, out);
}